// Round 1
// baseline (449.410 us; speedup 1.0000x reference)
//
#include <hip/hip_runtime.h>

typedef __bf16 bf16_t;
typedef __bf16 bf16x8 __attribute__((ext_vector_type(8)));
typedef float f32x4 __attribute__((ext_vector_type(4)));

#define MFMA(a, b, c) __builtin_amdgcn_mfma_f32_16x16x32_bf16((a), (b), (c), 0, 0, 0)

#define E_ROWS 640000
#define BM 128

static __device__ __forceinline__ bf16x8 cvt8(float4 a, float4 b) {
  bf16x8 r;
  r[0] = (bf16_t)a.x; r[1] = (bf16_t)a.y; r[2] = (bf16_t)a.z; r[3] = (bf16_t)a.w;
  r[4] = (bf16_t)b.x; r[5] = (bf16_t)b.y; r[6] = (bf16_t)b.z; r[7] = (bf16_t)b.w;
  return r;
}

// ws layout (bf16 elems): Wm1t @0      [128 n][256 k]
//                         Wm2t @32768  [128 n][128 k]
//                         Wu1t @49152  [128 n][256 k]
//                         Wu2t @81920  [128 n][128 k]
__global__ __launch_bounds__(256) void prep_weights(
    const float* __restrict__ Wm1, const float* __restrict__ Wm2,
    const float* __restrict__ Wu1, const float* __restrict__ Wu2,
    bf16_t* __restrict__ wt) {
  int idx = blockIdx.x * 256 + threadIdx.x;
  if (idx < 32768) {
    int n = idx >> 8, k = idx & 255;
    wt[idx] = (bf16_t)Wm1[k * 128 + n];
  } else if (idx < 49152) {
    int j = idx - 32768; int n = j >> 7, k = j & 127;
    wt[idx] = (bf16_t)Wm2[k * 128 + n];
  } else if (idx < 81920) {
    int j = idx - 49152; int n = j >> 8, k = j & 255;
    wt[idx] = (bf16_t)Wu1[k * 128 + n];
  } else if (idx < 98304) {
    int j = idx - 81920; int n = j >> 7, k = j & 127;
    wt[idx] = (bf16_t)Wu2[k * 128 + n];
  }
}

__global__ __launch_bounds__(256) void fused_mp(
    const float* __restrict__ hself, const float* __restrict__ hother,
    const bf16_t* __restrict__ wt,
    const float* __restrict__ bm1, const float* __restrict__ bm2,
    const float* __restrict__ bu1, const float* __restrict__ bu2,
    float* __restrict__ out) {
  // 64KB + 32KB + 32KB = 128KB LDS
  __shared__ bf16_t sW1[128 * 256];  // Wt1 [n][k], XOR-swizzled
  __shared__ bf16_t sW2[128 * 128];  // Wt2 [n][k], XOR-swizzled
  __shared__ bf16_t conv[128 * 128]; // per-wave 32-row stripes, layout shuffle

  const int tid = threadIdx.x;
  const int lane = tid & 63;
  const int wave = tid >> 6;
  const int col16 = lane & 15;  // A-row / B-col / C-col within 16-tile
  const int kgrp = lane >> 4;   // 0..3 k-group (8 elems each)
  const int rowloc0 = wave * 32;
  const int swz = (col16 & 7) << 4;

  const bf16x8* gwt = (const bf16x8*)wt;

  // ---- stage Wm1t, Wm2t into LDS (swizzled) ----
  #pragma unroll
  for (int i = 0; i < 16; ++i) {
    int c = tid + i * 256;                 // 4096 chunks of 16B
    int n = c >> 5;                        // 32 chunks per 256-elem row
    int byteoff = (c << 4) ^ ((n & 7) << 4);
    *(bf16x8*)((char*)sW1 + byteoff) = gwt[c];
  }
  #pragma unroll
  for (int i = 0; i < 8; ++i) {
    int c = tid + i * 256;                 // 2048 chunks
    int n = c >> 4;                        // 16 chunks per 128-elem row
    int byteoff = (c << 4) ^ ((n & 7) << 4);
    *(bf16x8*)((char*)sW2 + byteoff) = gwt[4096 + c];
  }

  // ---- biases (col-indexed per lane) ----
  float bm1v[8], bm2v[8], bu1v[8], bu2v[8];
  #pragma unroll
  for (int n = 0; n < 8; ++n) {
    bm1v[n] = bm1[n * 16 + col16];
    bm2v[n] = bm2[n * 16 + col16];
    bu1v[n] = bu1[n * 16 + col16];
    bu2v[n] = bu2[n * 16 + col16];
  }

  // ---- load A fragments for hself/hother, f32 -> bf16 ----
  bf16x8 hsf[2][4], hof[2][4];
  {
    float4 t0[2][4], t1[2][4], u0[2][4], u1[2][4];
    #pragma unroll
    for (int rb = 0; rb < 2; ++rb) {
      #pragma unroll
      for (int ks = 0; ks < 4; ++ks) {
        size_t row = (size_t)blockIdx.x * BM + rowloc0 + rb * 16 + col16;
        const float* p = hself + row * 128 + ks * 32 + kgrp * 8;
        t0[rb][ks] = *(const float4*)p;
        t1[rb][ks] = *(const float4*)(p + 4);
        const float* q = hother + row * 128 + ks * 32 + kgrp * 8;
        u0[rb][ks] = *(const float4*)q;
        u1[rb][ks] = *(const float4*)(q + 4);
      }
    }
    #pragma unroll
    for (int rb = 0; rb < 2; ++rb) {
      #pragma unroll
      for (int ks = 0; ks < 4; ++ks) {
        hsf[rb][ks] = cvt8(t0[rb][ks], t1[rb][ks]);
        hof[rb][ks] = cvt8(u0[rb][ks], u1[rb][ks]);
      }
    }
  }

  __syncthreads();  // weights staged

  f32x4 acc[2][8];

  // ================= GEMM1: h1 = relu([hs|ho] @ Wm1 + bm1) =================
  #pragma unroll
  for (int rb = 0; rb < 2; ++rb)
    #pragma unroll
    for (int n = 0; n < 8; ++n)
      acc[rb][n] = (f32x4){0.f, 0.f, 0.f, 0.f};

  #pragma unroll
  for (int ks = 0; ks < 8; ++ks) {
    bf16x8 b[8];
    #pragma unroll
    for (int n = 0; n < 8; ++n)
      b[n] = *(const bf16x8*)((const char*)sW1 +
              ((((n * 16 + col16) << 9) + ks * 64 + kgrp * 16) ^ swz));
    bf16x8 a0 = (ks < 4) ? hsf[0][ks & 3] : hof[0][ks & 3];
    bf16x8 a1 = (ks < 4) ? hsf[1][ks & 3] : hof[1][ks & 3];
    #pragma unroll
    for (int n = 0; n < 8; ++n) {
      acc[0][n] = MFMA(a0, b[n], acc[0][n]);
      acc[1][n] = MFMA(a1, b[n], acc[1][n]);
    }
  }

  // epilogue: relu(+bm1) -> conv stripe (C-layout writes)
  #pragma unroll
  for (int rb = 0; rb < 2; ++rb)
    #pragma unroll
    for (int n = 0; n < 8; ++n)
      #pragma unroll
      for (int e = 0; e < 4; ++e) {
        float v = fmaxf(acc[rb][n][e] + bm1v[n], 0.f);
        int r = rowloc0 + rb * 16 + kgrp * 4 + e;
        int byteoff = ((r << 8) + (n * 16 + col16) * 2) ^ ((r & 7) << 4);
        *(bf16_t*)((char*)conv + byteoff) = (bf16_t)v;
      }
  asm volatile("s_waitcnt lgkmcnt(0)" ::: "memory");

  bf16x8 h1f[2][4];
  #pragma unroll
  for (int rb = 0; rb < 2; ++rb)
    #pragma unroll
    for (int ks = 0; ks < 4; ++ks) {
      int r = rowloc0 + rb * 16 + col16;
      h1f[rb][ks] = *(const bf16x8*)((const char*)conv +
                    (((r << 8) + ks * 64 + kgrp * 16) ^ swz));
    }

  // ================= GEMM2: msg = h1 @ Wm2 + bm2 =================
  #pragma unroll
  for (int rb = 0; rb < 2; ++rb)
    #pragma unroll
    for (int n = 0; n < 8; ++n)
      acc[rb][n] = (f32x4){0.f, 0.f, 0.f, 0.f};

  #pragma unroll
  for (int ks = 0; ks < 4; ++ks) {
    bf16x8 b[8];
    #pragma unroll
    for (int n = 0; n < 8; ++n)
      b[n] = *(const bf16x8*)((const char*)sW2 +
              ((((n * 16 + col16) << 8) + ks * 64 + kgrp * 16) ^ swz));
    #pragma unroll
    for (int n = 0; n < 8; ++n) {
      acc[0][n] = MFMA(h1f[0][ks], b[n], acc[0][n]);
      acc[1][n] = MFMA(h1f[1][ks], b[n], acc[1][n]);
    }
  }

  // epilogue: +bm2 (no relu) -> conv -> msg A-frags
  #pragma unroll
  for (int rb = 0; rb < 2; ++rb)
    #pragma unroll
    for (int n = 0; n < 8; ++n)
      #pragma unroll
      for (int e = 0; e < 4; ++e) {
        float v = acc[rb][n][e] + bm2v[n];
        int r = rowloc0 + rb * 16 + kgrp * 4 + e;
        int byteoff = ((r << 8) + (n * 16 + col16) * 2) ^ ((r & 7) << 4);
        *(bf16_t*)((char*)conv + byteoff) = (bf16_t)v;
      }
  asm volatile("s_waitcnt lgkmcnt(0)" ::: "memory");

  bf16x8 msgf[2][4];
  #pragma unroll
  for (int rb = 0; rb < 2; ++rb)
    #pragma unroll
    for (int ks = 0; ks < 4; ++ks) {
      int r = rowloc0 + rb * 16 + col16;
      msgf[rb][ks] = *(const bf16x8*)((const char*)conv +
                     (((r << 8) + ks * 64 + kgrp * 16) ^ swz));
    }

  // ---- phase swap: restage Wu1t, Wu2t ----
  __syncthreads();
  #pragma unroll
  for (int i = 0; i < 16; ++i) {
    int c = tid + i * 256;
    int n = c >> 5;
    int byteoff = (c << 4) ^ ((n & 7) << 4);
    *(bf16x8*)((char*)sW1 + byteoff) = gwt[6144 + c];
  }
  #pragma unroll
  for (int i = 0; i < 8; ++i) {
    int c = tid + i * 256;
    int n = c >> 4;
    int byteoff = (c << 4) ^ ((n & 7) << 4);
    *(bf16x8*)((char*)sW2 + byteoff) = gwt[10240 + c];
  }
  __syncthreads();

  // ================= GEMM3: h2 = relu([hs|msg] @ Wu1 + bu1) =================
  #pragma unroll
  for (int rb = 0; rb < 2; ++rb)
    #pragma unroll
    for (int n = 0; n < 8; ++n)
      acc[rb][n] = (f32x4){0.f, 0.f, 0.f, 0.f};

  #pragma unroll
  for (int ks = 0; ks < 8; ++ks) {
    bf16x8 b[8];
    #pragma unroll
    for (int n = 0; n < 8; ++n)
      b[n] = *(const bf16x8*)((const char*)sW1 +
              ((((n * 16 + col16) << 9) + ks * 64 + kgrp * 16) ^ swz));
    bf16x8 a0 = (ks < 4) ? hsf[0][ks & 3] : msgf[0][ks & 3];
    bf16x8 a1 = (ks < 4) ? hsf[1][ks & 3] : msgf[1][ks & 3];
    #pragma unroll
    for (int n = 0; n < 8; ++n) {
      acc[0][n] = MFMA(a0, b[n], acc[0][n]);
      acc[1][n] = MFMA(a1, b[n], acc[1][n]);
    }
  }

  #pragma unroll
  for (int rb = 0; rb < 2; ++rb)
    #pragma unroll
    for (int n = 0; n < 8; ++n)
      #pragma unroll
      for (int e = 0; e < 4; ++e) {
        float v = fmaxf(acc[rb][n][e] + bu1v[n], 0.f);
        int r = rowloc0 + rb * 16 + kgrp * 4 + e;
        int byteoff = ((r << 8) + (n * 16 + col16) * 2) ^ ((r & 7) << 4);
        *(bf16_t*)((char*)conv + byteoff) = (bf16_t)v;
      }
  asm volatile("s_waitcnt lgkmcnt(0)" ::: "memory");

  bf16x8 h2f[2][4];
  #pragma unroll
  for (int rb = 0; rb < 2; ++rb)
    #pragma unroll
    for (int ks = 0; ks < 4; ++ks) {
      int r = rowloc0 + rb * 16 + col16;
      h2f[rb][ks] = *(const bf16x8*)((const char*)conv +
                    (((r << 8) + ks * 64 + kgrp * 16) ^ swz));
    }

  // ================= GEMM4: out = h2 @ Wu2 + bu2 =================
  #pragma unroll
  for (int rb = 0; rb < 2; ++rb)
    #pragma unroll
    for (int n = 0; n < 8; ++n)
      acc[rb][n] = (f32x4){0.f, 0.f, 0.f, 0.f};

  #pragma unroll
  for (int ks = 0; ks < 4; ++ks) {
    bf16x8 b[8];
    #pragma unroll
    for (int n = 0; n < 8; ++n)
      b[n] = *(const bf16x8*)((const char*)sW2 +
              ((((n * 16 + col16) << 8) + ks * 64 + kgrp * 16) ^ swz));
    #pragma unroll
    for (int n = 0; n < 8; ++n) {
      acc[0][n] = MFMA(h2f[0][ks], b[n], acc[0][n]);
      acc[1][n] = MFMA(h2f[1][ks], b[n], acc[1][n]);
    }
  }

  // final store (f32), 64B-coalesced per quarter-wave
  #pragma unroll
  for (int rb = 0; rb < 2; ++rb)
    #pragma unroll
    for (int n = 0; n < 8; ++n)
      #pragma unroll
      for (int e = 0; e < 4; ++e) {
        size_t r = (size_t)blockIdx.x * BM + rowloc0 + rb * 16 + kgrp * 4 + e;
        out[r * 128 + n * 16 + col16] = acc[rb][n][e] + bu2v[n];
      }
}

extern "C" void kernel_launch(void* const* d_in, const int* in_sizes, int n_in,
                              void* d_out, int out_size, void* d_ws, size_t ws_size,
                              hipStream_t stream) {
  const float* hself  = (const float*)d_in[0];
  const float* hother = (const float*)d_in[1];
  const float* Wm1 = (const float*)d_in[2];
  const float* bm1 = (const float*)d_in[3];
  const float* Wm2 = (const float*)d_in[4];
  const float* bm2 = (const float*)d_in[5];
  const float* Wu1 = (const float*)d_in[6];
  const float* bu1 = (const float*)d_in[7];
  const float* Wu2 = (const float*)d_in[8];
  const float* bu2 = (const float*)d_in[9];
  float* out = (float*)d_out;
  bf16_t* wt = (bf16_t*)d_ws;  // 196608 B of bf16 weights

  prep_weights<<<384, 256, 0, stream>>>(Wm1, Wm2, Wu1, Wu2, wt);
  fused_mp<<<E_ROWS / BM, 256, 0, stream>>>(hself, hother, wt,
                                            bm1, bm2, bu1, bu2, out);
}

// Round 2
// 350.079 us; speedup vs baseline: 1.2837x; 1.2837x over previous
//
#include <hip/hip_runtime.h>

typedef __bf16 bf16_t;
typedef __bf16 bf16x8 __attribute__((ext_vector_type(8)));
typedef float f32x4 __attribute__((ext_vector_type(4)));

#define MFMA(a, b, c) __builtin_amdgcn_mfma_f32_16x16x32_bf16((a), (b), (c), 0, 0, 0)

#define E_ROWS 640000
#define BM 128

static __device__ __forceinline__ bf16x8 cvt8(float4 a, float4 b) {
  bf16x8 r;
  r[0] = (bf16_t)a.x; r[1] = (bf16_t)a.y; r[2] = (bf16_t)a.z; r[3] = (bf16_t)a.w;
  r[4] = (bf16_t)b.x; r[5] = (bf16_t)b.y; r[6] = (bf16_t)b.z; r[7] = (bf16_t)b.w;
  return r;
}

// Fragment-ordered weights in ws. Fragment id f:
//   GEMM1 (Wm1): f =   0 + ks*8 + nb   (ks 0..7, nb 0..7)
//   GEMM2 (Wm2): f =  64 + ks*8 + nb   (ks 0..3)
//   GEMM3 (Wu1): f =  96 + ks*8 + nb   (ks 0..7)
//   GEMM4 (Wu2): f = 160 + ks*8 + nb   (ks 0..3)
// chunk c = f*64 + lane holds 8 bf16: W[k][n], k = 32*ks + 8*(lane>>4) + j,
// n = 16*nb + (lane&15). One 16B load per lane = B-frag for mfma_16x16x32.
__global__ __launch_bounds__(256) void prep_weights(
    const float* __restrict__ Wm1, const float* __restrict__ Wm2,
    const float* __restrict__ Wu1, const float* __restrict__ Wu2,
    bf16_t* __restrict__ wt) {
  int c = blockIdx.x * 256 + threadIdx.x;  // 12288 chunks of 16B
  if (c >= 12288) return;
  int lane = c & 63, f = c >> 6;
  const float* W; int base;
  if (f < 64)       { W = Wm1; base = 0;   }
  else if (f < 96)  { W = Wm2; base = 64;  }
  else if (f < 160) { W = Wu1; base = 96;  }
  else              { W = Wu2; base = 160; }
  int fl = f - base;
  int ks = fl >> 3, nb = fl & 7;
  int k0 = 32 * ks + 8 * (lane >> 4);
  int n  = 16 * nb + (lane & 15);
  bf16x8 v;
  #pragma unroll
  for (int j = 0; j < 8; ++j) v[j] = (bf16_t)W[(size_t)(k0 + j) * 128 + n];
  ((bf16x8*)wt)[c] = v;
}

static __device__ __forceinline__ void loadB(bf16x8* dst, const bf16x8* gb,
                                             int fragbase, int lane) {
  #pragma unroll
  for (int n = 0; n < 8; ++n) dst[n] = gb[(size_t)(fragbase + n) * 64 + lane];
}

__global__ __launch_bounds__(256, 2) void fused_mp(
    const float* __restrict__ hself, const float* __restrict__ hother,
    const bf16_t* __restrict__ wt,
    const float* __restrict__ bm1, const float* __restrict__ bm2,
    const float* __restrict__ bu1, const float* __restrict__ bu2,
    float* __restrict__ out) {
  // only LDS: per-wave 32-row stripes for C-layout -> A-layout shuffle (32 KB)
  __shared__ bf16_t conv[128 * 128];

  const int tid = threadIdx.x;
  const int lane = tid & 63;
  const int wave = tid >> 6;
  const int col16 = lane & 15;  // A-row / B-col / C-col within 16-tile
  const int kgrp = lane >> 4;   // 0..3 k-group (8 elems each)
  const int rowloc0 = wave * 32;
  const int swz = (col16 & 7) << 4;

  const bf16x8* gb = (const bf16x8*)wt;

  // ---- biases (col-indexed per lane) ----
  float bm1v[8], bm2v[8], bu1v[8], bu2v[8];
  #pragma unroll
  for (int n = 0; n < 8; ++n) {
    bm1v[n] = bm1[n * 16 + col16];
    bm2v[n] = bm2[n * 16 + col16];
    bu1v[n] = bu1[n * 16 + col16];
    bu2v[n] = bu2[n * 16 + col16];
  }

  // ---- load A fragments for hself/hother, f32 -> bf16 ----
  bf16x8 hsf[2][4], hof[2][4];
  {
    float4 t0[2][4], t1[2][4], u0[2][4], u1[2][4];
    #pragma unroll
    for (int rb = 0; rb < 2; ++rb) {
      #pragma unroll
      for (int ks = 0; ks < 4; ++ks) {
        size_t row = (size_t)blockIdx.x * BM + rowloc0 + rb * 16 + col16;
        const float* p = hself + row * 128 + ks * 32 + kgrp * 8;
        t0[rb][ks] = *(const float4*)p;
        t1[rb][ks] = *(const float4*)(p + 4);
        const float* q = hother + row * 128 + ks * 32 + kgrp * 8;
        u0[rb][ks] = *(const float4*)q;
        u1[rb][ks] = *(const float4*)(q + 4);
      }
    }
    #pragma unroll
    for (int rb = 0; rb < 2; ++rb) {
      #pragma unroll
      for (int ks = 0; ks < 4; ++ks) {
        hsf[rb][ks] = cvt8(t0[rb][ks], t1[rb][ks]);
        hof[rb][ks] = cvt8(u0[rb][ks], u1[rb][ks]);
      }
    }
  }

  f32x4 acc[2][8];
  bf16x8 bA[8], bB[8];

  // ================= GEMM1: h1 = relu([hs|ho] @ Wm1 + bm1) =================
  #pragma unroll
  for (int rb = 0; rb < 2; ++rb)
    #pragma unroll
    for (int n = 0; n < 8; ++n)
      acc[rb][n] = (f32x4){0.f, 0.f, 0.f, 0.f};

  loadB(bA, gb, 0, lane);
  #pragma unroll
  for (int ks = 0; ks < 8; ++ks) {
    bf16x8* bc = (ks & 1) ? bB : bA;
    bf16x8* bn = (ks & 1) ? bA : bB;
    if (ks < 7) loadB(bn, gb, (ks + 1) * 8, lane);
    bf16x8 a0 = (ks < 4) ? hsf[0][ks & 3] : hof[0][ks & 3];
    bf16x8 a1 = (ks < 4) ? hsf[1][ks & 3] : hof[1][ks & 3];
    #pragma unroll
    for (int n = 0; n < 8; ++n) {
      acc[0][n] = MFMA(a0, bc[n], acc[0][n]);
      acc[1][n] = MFMA(a1, bc[n], acc[1][n]);
    }
  }

  // epilogue: relu(+bm1) -> conv stripe (C-layout writes)
  #pragma unroll
  for (int rb = 0; rb < 2; ++rb)
    #pragma unroll
    for (int n = 0; n < 8; ++n)
      #pragma unroll
      for (int e = 0; e < 4; ++e) {
        float v = fmaxf(acc[rb][n][e] + bm1v[n], 0.f);
        int r = rowloc0 + rb * 16 + kgrp * 4 + e;
        int byteoff = ((r << 8) + (n * 16 + col16) * 2) ^ ((r & 7) << 4);
        *(bf16_t*)((char*)conv + byteoff) = (bf16_t)v;
      }
  asm volatile("s_waitcnt lgkmcnt(0)" ::: "memory");

  bf16x8 h1f[2][4];
  #pragma unroll
  for (int rb = 0; rb < 2; ++rb)
    #pragma unroll
    for (int ks = 0; ks < 4; ++ks) {
      int r = rowloc0 + rb * 16 + col16;
      h1f[rb][ks] = *(const bf16x8*)((const char*)conv +
                    (((r << 8) + ks * 64 + kgrp * 16) ^ swz));
    }

  // ================= GEMM2: msg = h1 @ Wm2 + bm2 =================
  #pragma unroll
  for (int rb = 0; rb < 2; ++rb)
    #pragma unroll
    for (int n = 0; n < 8; ++n)
      acc[rb][n] = (f32x4){0.f, 0.f, 0.f, 0.f};

  loadB(bA, gb, 64, lane);
  #pragma unroll
  for (int ks = 0; ks < 4; ++ks) {
    bf16x8* bc = (ks & 1) ? bB : bA;
    bf16x8* bn = (ks & 1) ? bA : bB;
    if (ks < 3) loadB(bn, gb, 64 + (ks + 1) * 8, lane);
    #pragma unroll
    for (int n = 0; n < 8; ++n) {
      acc[0][n] = MFMA(h1f[0][ks], bc[n], acc[0][n]);
      acc[1][n] = MFMA(h1f[1][ks], bc[n], acc[1][n]);
    }
  }

  // epilogue: +bm2 (no relu) -> conv -> msg A-frags
  #pragma unroll
  for (int rb = 0; rb < 2; ++rb)
    #pragma unroll
    for (int n = 0; n < 8; ++n)
      #pragma unroll
      for (int e = 0; e < 4; ++e) {
        float v = acc[rb][n][e] + bm2v[n];
        int r = rowloc0 + rb * 16 + kgrp * 4 + e;
        int byteoff = ((r << 8) + (n * 16 + col16) * 2) ^ ((r & 7) << 4);
        *(bf16_t*)((char*)conv + byteoff) = (bf16_t)v;
      }
  asm volatile("s_waitcnt lgkmcnt(0)" ::: "memory");

  bf16x8 msgf[2][4];
  #pragma unroll
  for (int rb = 0; rb < 2; ++rb)
    #pragma unroll
    for (int ks = 0; ks < 4; ++ks) {
      int r = rowloc0 + rb * 16 + col16;
      msgf[rb][ks] = *(const bf16x8*)((const char*)conv +
                     (((r << 8) + ks * 64 + kgrp * 16) ^ swz));
    }

  // ================= GEMM3: h2 = relu([hs|msg] @ Wu1 + bu1) =================
  #pragma unroll
  for (int rb = 0; rb < 2; ++rb)
    #pragma unroll
    for (int n = 0; n < 8; ++n)
      acc[rb][n] = (f32x4){0.f, 0.f, 0.f, 0.f};

  loadB(bA, gb, 96, lane);
  #pragma unroll
  for (int ks = 0; ks < 8; ++ks) {
    bf16x8* bc = (ks & 1) ? bB : bA;
    bf16x8* bn = (ks & 1) ? bA : bB;
    if (ks < 7) loadB(bn, gb, 96 + (ks + 1) * 8, lane);
    bf16x8 a0 = (ks < 4) ? hsf[0][ks & 3] : msgf[0][ks & 3];
    bf16x8 a1 = (ks < 4) ? hsf[1][ks & 3] : msgf[1][ks & 3];
    #pragma unroll
    for (int n = 0; n < 8; ++n) {
      acc[0][n] = MFMA(a0, bc[n], acc[0][n]);
      acc[1][n] = MFMA(a1, bc[n], acc[1][n]);
    }
  }

  #pragma unroll
  for (int rb = 0; rb < 2; ++rb)
    #pragma unroll
    for (int n = 0; n < 8; ++n)
      #pragma unroll
      for (int e = 0; e < 4; ++e) {
        float v = fmaxf(acc[rb][n][e] + bu1v[n], 0.f);
        int r = rowloc0 + rb * 16 + kgrp * 4 + e;
        int byteoff = ((r << 8) + (n * 16 + col16) * 2) ^ ((r & 7) << 4);
        *(bf16_t*)((char*)conv + byteoff) = (bf16_t)v;
      }
  asm volatile("s_waitcnt lgkmcnt(0)" ::: "memory");

  bf16x8 h2f[2][4];
  #pragma unroll
  for (int rb = 0; rb < 2; ++rb)
    #pragma unroll
    for (int ks = 0; ks < 4; ++ks) {
      int r = rowloc0 + rb * 16 + col16;
      h2f[rb][ks] = *(const bf16x8*)((const char*)conv +
                    (((r << 8) + ks * 64 + kgrp * 16) ^ swz));
    }

  // ================= GEMM4: out = h2 @ Wu2 + bu2 =================
  #pragma unroll
  for (int rb = 0; rb < 2; ++rb)
    #pragma unroll
    for (int n = 0; n < 8; ++n)
      acc[rb][n] = (f32x4){0.f, 0.f, 0.f, 0.f};

  loadB(bA, gb, 160, lane);
  #pragma unroll
  for (int ks = 0; ks < 4; ++ks) {
    bf16x8* bc = (ks & 1) ? bB : bA;
    bf16x8* bn = (ks & 1) ? bA : bB;
    if (ks < 3) loadB(bn, gb, 160 + (ks + 1) * 8, lane);
    #pragma unroll
    for (int n = 0; n < 8; ++n) {
      acc[0][n] = MFMA(h2f[0][ks], bc[n], acc[0][n]);
      acc[1][n] = MFMA(h2f[1][ks], bc[n], acc[1][n]);
    }
  }

  // final store (f32), 64B-coalesced per quarter-wave
  #pragma unroll
  for (int rb = 0; rb < 2; ++rb)
    #pragma unroll
    for (int n = 0; n < 8; ++n)
      #pragma unroll
      for (int e = 0; e < 4; ++e) {
        size_t r = (size_t)blockIdx.x * BM + rowloc0 + rb * 16 + kgrp * 4 + e;
        out[r * 128 + n * 16 + col16] = acc[rb][n][e] + bu2v[n];
      }
}

extern "C" void kernel_launch(void* const* d_in, const int* in_sizes, int n_in,
                              void* d_out, int out_size, void* d_ws, size_t ws_size,
                              hipStream_t stream) {
  const float* hself  = (const float*)d_in[0];
  const float* hother = (const float*)d_in[1];
  const float* Wm1 = (const float*)d_in[2];
  const float* bm1 = (const float*)d_in[3];
  const float* Wm2 = (const float*)d_in[4];
  const float* bm2 = (const float*)d_in[5];
  const float* Wu1 = (const float*)d_in[6];
  const float* bu1 = (const float*)d_in[7];
  const float* Wu2 = (const float*)d_in[8];
  const float* bu2 = (const float*)d_in[9];
  float* out = (float*)d_out;
  bf16_t* wt = (bf16_t*)d_ws;  // 196608 B of fragment-ordered bf16 weights

  prep_weights<<<48, 256, 0, stream>>>(Wm1, Wm2, Wu1, Wu2, wt);
  fused_mp<<<E_ROWS / BM, 256, 0, stream>>>(hself, hother, wt,
                                            bm1, bm2, bu1, bu2, out);
}

// Round 3
// 335.364 us; speedup vs baseline: 1.3401x; 1.0439x over previous
//
#include <hip/hip_runtime.h>

typedef __bf16 bf16_t;
typedef __bf16 bf16x8 __attribute__((ext_vector_type(8)));
typedef float f32x4 __attribute__((ext_vector_type(4)));

#define MFMA(a, b, c) __builtin_amdgcn_mfma_f32_16x16x32_bf16((a), (b), (c), 0, 0, 0)

#define E_ROWS 640000
#define BM 128

static __device__ __forceinline__ bf16x8 cvt8(float4 a, float4 b) {
  bf16x8 r;
  r[0] = (bf16_t)a.x; r[1] = (bf16_t)a.y; r[2] = (bf16_t)a.z; r[3] = (bf16_t)a.w;
  r[4] = (bf16_t)b.x; r[5] = (bf16_t)b.y; r[6] = (bf16_t)b.z; r[7] = (bf16_t)b.w;
  return r;
}

static __device__ __forceinline__ unsigned int pk2(float a, float b) {
  unsigned short ua = __builtin_bit_cast(unsigned short, (bf16_t)a);
  unsigned short ub = __builtin_bit_cast(unsigned short, (bf16_t)b);
  return ((unsigned int)ub << 16) | ua;
}

// Fragment-ordered weights in ws (unchanged layout; data identical whether the
// fragment is used as MFMA A-operand (Wt rows = output features) or B-operand).
//   GEMM1 (Wm1): f =   0 + ks*8 + nb   (ks 0..7, nb 0..7)
//   GEMM2 (Wm2): f =  64 + ks*8 + nb   (ks 0..3)
//   GEMM3 (Wu1): f =  96 + ks*8 + nb   (ks 0..7)
//   GEMM4 (Wu2): f = 160 + ks*8 + nb   (ks 0..3)
// chunk c = f*64 + lane holds 8 bf16: W[k][n], k = 32*ks + 8*(lane>>4) + j,
// n = 16*nb + (lane&15).
__global__ __launch_bounds__(256) void prep_weights(
    const float* __restrict__ Wm1, const float* __restrict__ Wm2,
    const float* __restrict__ Wu1, const float* __restrict__ Wu2,
    bf16_t* __restrict__ wt) {
  int c = blockIdx.x * 256 + threadIdx.x;  // 12288 chunks of 16B
  if (c >= 12288) return;
  int lane = c & 63, f = c >> 6;
  const float* W; int base;
  if (f < 64)       { W = Wm1; base = 0;   }
  else if (f < 96)  { W = Wm2; base = 64;  }
  else if (f < 160) { W = Wu1; base = 96;  }
  else              { W = Wu2; base = 160; }
  int fl = f - base;
  int ks = fl >> 3, nb = fl & 7;
  int k0 = 32 * ks + 8 * (lane >> 4);
  int n  = 16 * nb + (lane & 15);
  bf16x8 v;
  #pragma unroll
  for (int j = 0; j < 8; ++j) v[j] = (bf16_t)W[(size_t)(k0 + j) * 128 + n];
  ((bf16x8*)wt)[c] = v;
}

static __device__ __forceinline__ void loadW(bf16x8* dst, const bf16x8* gb,
                                             int fragbase, int lane) {
  #pragma unroll
  for (int n = 0; n < 8; ++n) dst[n] = gb[(fragbase + n) * 64 + lane];
}

// Transposed-chain fused kernel: every GEMM computes h^T = W^T * x^T.
// MFMA A-operand = W-frag, B-operand = x-frag. D (C-layout) holds, for lane
// (c = lane&15, g = lane>>4): h[rowbase + 16*mt + c][feature 16*nb + 4*g + e].
// Repack to next GEMM's B-frag via per-wave LDS u64 scatter (no barriers).
__global__ __launch_bounds__(256, 2) void fused_mp(
    const float* __restrict__ hself, const float* __restrict__ hother,
    const bf16_t* __restrict__ wt,
    const float* __restrict__ bm1, const float* __restrict__ bm2,
    const float* __restrict__ bu1, const float* __restrict__ bu2,
    float* __restrict__ out) {
  // per-wave repack region: [mt(2)][ks(4)][lane(64)] * 16B = 8 KB; 4 waves = 32 KB
  __shared__ bf16_t repack[4 * 4096];

  const int tid = threadIdx.x;
  const int lane = tid & 63;
  const int wave = tid >> 6;
  const int c = lane & 15;
  const int g = lane >> 4;

  char* myrep = (char*)(repack + wave * 4096);
  const bf16x8* gb = (const bf16x8*)wt;
  const size_t rowbase = (size_t)blockIdx.x * BM + wave * 32;

  // ---- load x fragments (B-operand layout == old A layout), f32 -> bf16 ----
  bf16x8 hsf[2][4], hof[2][4];
  {
    float4 t0[2][4], t1[2][4], u0[2][4], u1[2][4];
    #pragma unroll
    for (int mt = 0; mt < 2; ++mt) {
      #pragma unroll
      for (int ks = 0; ks < 4; ++ks) {
        size_t row = rowbase + mt * 16 + c;
        const float* p = hself + row * 128 + ks * 32 + g * 8;
        t0[mt][ks] = *(const float4*)p;
        t1[mt][ks] = *(const float4*)(p + 4);
        const float* q = hother + row * 128 + ks * 32 + g * 8;
        u0[mt][ks] = *(const float4*)q;
        u1[mt][ks] = *(const float4*)(q + 4);
      }
    }
    #pragma unroll
    for (int mt = 0; mt < 2; ++mt) {
      #pragma unroll
      for (int ks = 0; ks < 4; ++ks) {
        hsf[mt][ks] = cvt8(t0[mt][ks], t1[mt][ks]);
        hof[mt][ks] = cvt8(u0[mt][ks], u1[mt][ks]);
      }
    }
  }

  f32x4 acc[2][8];
  bf16x8 wA[8], wB[8];

  // ============ GEMM1: h1^T = Wm1^T [hs|ho]^T  (+bm1 via acc init, relu) ====
  #pragma unroll
  for (int nb = 0; nb < 8; ++nb) {
    float4 b4 = *(const float4*)(bm1 + nb * 16 + g * 4);
    acc[0][nb] = (f32x4){b4.x, b4.y, b4.z, b4.w};
    acc[1][nb] = acc[0][nb];
  }
  loadW(wA, gb, 0, lane);
  #pragma unroll
  for (int ks = 0; ks < 8; ++ks) {
    bf16x8* wc = (ks & 1) ? wB : wA;
    bf16x8* wn = (ks & 1) ? wA : wB;
    if (ks < 7) loadW(wn, gb, (ks + 1) * 8, lane);
    bf16x8 x0 = (ks < 4) ? hsf[0][ks & 3] : hof[0][ks & 3];
    bf16x8 x1 = (ks < 4) ? hsf[1][ks & 3] : hof[1][ks & 3];
    #pragma unroll
    for (int nb = 0; nb < 8; ++nb) {
      acc[0][nb] = MFMA(wc[nb], x0, acc[0][nb]);
      acc[1][nb] = MFMA(wc[nb], x1, acc[1][nb]);
    }
  }

  // repack epilogue 1: relu, pack to bf16 pairs, u64 scatter to B-frag layout
  #pragma unroll
  for (int mt = 0; mt < 2; ++mt)
    #pragma unroll
    for (int nb = 0; nb < 8; ++nb) {
      f32x4 v = acc[mt][nb];
      uint2 w;
      w.x = pk2(fmaxf(v[0], 0.f), fmaxf(v[1], 0.f));
      w.y = pk2(fmaxf(v[2], 0.f), fmaxf(v[3], 0.f));
      int dstlane = c + 16 * (2 * (nb & 1) + (g >> 1));
      int off = ((mt * 4 + (nb >> 1)) * 64 + dstlane) * 16 + (g & 1) * 8;
      *(uint2*)(myrep + off) = w;
    }
  asm volatile("s_waitcnt lgkmcnt(0)" ::: "memory");
  bf16x8 h1B[2][4];
  #pragma unroll
  for (int mt = 0; mt < 2; ++mt)
    #pragma unroll
    for (int ks = 0; ks < 4; ++ks)
      h1B[mt][ks] = *(const bf16x8*)(myrep + ((mt * 4 + ks) * 64 + lane) * 16);

  // ============ GEMM2: msg^T = Wm2^T h1^T  (+bm2, no relu) =================
  #pragma unroll
  for (int nb = 0; nb < 8; ++nb) {
    float4 b4 = *(const float4*)(bm2 + nb * 16 + g * 4);
    acc[0][nb] = (f32x4){b4.x, b4.y, b4.z, b4.w};
    acc[1][nb] = acc[0][nb];
  }
  loadW(wA, gb, 64, lane);
  #pragma unroll
  for (int ks = 0; ks < 4; ++ks) {
    bf16x8* wc = (ks & 1) ? wB : wA;
    bf16x8* wn = (ks & 1) ? wA : wB;
    if (ks < 3) loadW(wn, gb, 64 + (ks + 1) * 8, lane);
    #pragma unroll
    for (int nb = 0; nb < 8; ++nb) {
      acc[0][nb] = MFMA(wc[nb], h1B[0][ks], acc[0][nb]);
      acc[1][nb] = MFMA(wc[nb], h1B[1][ks], acc[1][nb]);
    }
  }

  // repack epilogue 2 (no relu) -> msg B-frags
  #pragma unroll
  for (int mt = 0; mt < 2; ++mt)
    #pragma unroll
    for (int nb = 0; nb < 8; ++nb) {
      f32x4 v = acc[mt][nb];
      uint2 w;
      w.x = pk2(v[0], v[1]);
      w.y = pk2(v[2], v[3]);
      int dstlane = c + 16 * (2 * (nb & 1) + (g >> 1));
      int off = ((mt * 4 + (nb >> 1)) * 64 + dstlane) * 16 + (g & 1) * 8;
      *(uint2*)(myrep + off) = w;
    }
  asm volatile("s_waitcnt lgkmcnt(0)" ::: "memory");
  bf16x8 msgB[2][4];
  #pragma unroll
  for (int mt = 0; mt < 2; ++mt)
    #pragma unroll
    for (int ks = 0; ks < 4; ++ks)
      msgB[mt][ks] = *(const bf16x8*)(myrep + ((mt * 4 + ks) * 64 + lane) * 16);

  // ============ GEMM3: h2^T = Wu1^T [hs|msg]^T  (+bu1, relu) ===============
  #pragma unroll
  for (int nb = 0; nb < 8; ++nb) {
    float4 b4 = *(const float4*)(bu1 + nb * 16 + g * 4);
    acc[0][nb] = (f32x4){b4.x, b4.y, b4.z, b4.w};
    acc[1][nb] = acc[0][nb];
  }
  loadW(wA, gb, 96, lane);
  #pragma unroll
  for (int ks = 0; ks < 8; ++ks) {
    bf16x8* wc = (ks & 1) ? wB : wA;
    bf16x8* wn = (ks & 1) ? wA : wB;
    if (ks < 7) loadW(wn, gb, 96 + (ks + 1) * 8, lane);
    bf16x8 x0 = (ks < 4) ? hsf[0][ks & 3] : msgB[0][ks & 3];
    bf16x8 x1 = (ks < 4) ? hsf[1][ks & 3] : msgB[1][ks & 3];
    #pragma unroll
    for (int nb = 0; nb < 8; ++nb) {
      acc[0][nb] = MFMA(wc[nb], x0, acc[0][nb]);
      acc[1][nb] = MFMA(wc[nb], x1, acc[1][nb]);
    }
  }

  // repack epilogue 3: relu -> h2 B-frags
  #pragma unroll
  for (int mt = 0; mt < 2; ++mt)
    #pragma unroll
    for (int nb = 0; nb < 8; ++nb) {
      f32x4 v = acc[mt][nb];
      uint2 w;
      w.x = pk2(fmaxf(v[0], 0.f), fmaxf(v[1], 0.f));
      w.y = pk2(fmaxf(v[2], 0.f), fmaxf(v[3], 0.f));
      int dstlane = c + 16 * (2 * (nb & 1) + (g >> 1));
      int off = ((mt * 4 + (nb >> 1)) * 64 + dstlane) * 16 + (g & 1) * 8;
      *(uint2*)(myrep + off) = w;
    }
  asm volatile("s_waitcnt lgkmcnt(0)" ::: "memory");
  bf16x8 h2B[2][4];
  #pragma unroll
  for (int mt = 0; mt < 2; ++mt)
    #pragma unroll
    for (int ks = 0; ks < 4; ++ks)
      h2B[mt][ks] = *(const bf16x8*)(myrep + ((mt * 4 + ks) * 64 + lane) * 16);

  // ============ GEMM4: out^T = Wu2^T h2^T  (+bu2) ==========================
  #pragma unroll
  for (int nb = 0; nb < 8; ++nb) {
    float4 b4 = *(const float4*)(bu2 + nb * 16 + g * 4);
    acc[0][nb] = (f32x4){b4.x, b4.y, b4.z, b4.w};
    acc[1][nb] = acc[0][nb];
  }
  loadW(wA, gb, 160, lane);
  #pragma unroll
  for (int ks = 0; ks < 4; ++ks) {
    bf16x8* wc = (ks & 1) ? wB : wA;
    bf16x8* wn = (ks & 1) ? wA : wB;
    if (ks < 3) loadW(wn, gb, 160 + (ks + 1) * 8, lane);
    #pragma unroll
    for (int nb = 0; nb < 8; ++nb) {
      acc[0][nb] = MFMA(wc[nb], h2B[0][ks], acc[0][nb]);
      acc[1][nb] = MFMA(wc[nb], h2B[1][ks], acc[1][nb]);
    }
  }

  // final store: per (mt,nb) a float4 at out[row][16nb+4g]; 16x64B segments/instr
  #pragma unroll
  for (int mt = 0; mt < 2; ++mt)
    #pragma unroll
    for (int nb = 0; nb < 8; ++nb) {
      size_t row = rowbase + mt * 16 + c;
      f32x4 v = acc[mt][nb];
      *(float4*)(out + row * 128 + nb * 16 + g * 4) =
          (float4){v[0], v[1], v[2], v[3]};
    }
}

extern "C" void kernel_launch(void* const* d_in, const int* in_sizes, int n_in,
                              void* d_out, int out_size, void* d_ws, size_t ws_size,
                              hipStream_t stream) {
  const float* hself  = (const float*)d_in[0];
  const float* hother = (const float*)d_in[1];
  const float* Wm1 = (const float*)d_in[2];
  const float* bm1 = (const float*)d_in[3];
  const float* Wm2 = (const float*)d_in[4];
  const float* bm2 = (const float*)d_in[5];
  const float* Wu1 = (const float*)d_in[6];
  const float* bu1 = (const float*)d_in[7];
  const float* Wu2 = (const float*)d_in[8];
  const float* bu2 = (const float*)d_in[9];
  float* out = (float*)d_out;
  bf16_t* wt = (bf16_t*)d_ws;  // 196608 B of fragment-ordered bf16 weights

  prep_weights<<<48, 256, 0, stream>>>(Wm1, Wm2, Wu1, Wu2, wt);
  fused_mp<<<E_ROWS / BM, 256, 0, stream>>>(hself, hother, wt,
                                            bm1, bm2, bu1, bu2, out);
}